// Round 6
// baseline (178.295 us; speedup 1.0000x reference)
//
#include <hip/hip_runtime.h>
#include <hip/hip_bf16.h>
#include <stdint.h>

#define N_NODES 100000
#define DEG 16
#define IN_F 128
#define OUT_F 64
#define ALPHA 0.2f

typedef __attribute__((ext_vector_type(8))) short short8;
typedef __attribute__((ext_vector_type(4))) float f32x4;
typedef __attribute__((ext_vector_type(4))) int i32x4;
typedef __attribute__((ext_vector_type(4))) unsigned int u32x4;
typedef __attribute__((ext_vector_type(2))) unsigned int u32x2;

static __device__ __forceinline__ unsigned int pack2bf(float lo, float hi) {
    // RTNE pair conversion; compiler emits v_cvt_pk_bf16_f32
    __hip_bfloat162 h = __float22bfloat162_rn(make_float2(lo, hi));
    unsigned int u; __builtin_memcpy(&u, &h, 4); return u;
}
static __device__ __forceinline__ unsigned short f2bf(float f) {
    __hip_bfloat16 h = __float2bfloat16(f);   // RTNE
    unsigned short u; __builtin_memcpy(&u, &h, 2); return u;
}

// Prep: w -> bf16 (all blocks); v1 = w^T a1w (block 0).
// a1 = feat@a1w = x@(w^T a1w) = x@v1  -- exact algebraic refactor, f32 throughout.
__global__ __launch_bounds__(256) void prep_kernel(
    const float* __restrict__ w, const float* __restrict__ a1w,
    unsigned short* __restrict__ wb, float* __restrict__ v1)
{
    int idx = blockIdx.x * 256 + threadIdx.x;
    if (idx < OUT_F * IN_F) wb[idx] = f2bf(w[idx]);
    if (blockIdx.x == 0 && threadIdx.x < IN_F) {
        int k = threadIdx.x;
        float acc = 0.f;
        #pragma unroll
        for (int f = 0; f < OUT_F; ++f) acc += w[f * IN_F + k] * a1w[f];
        v1[k] = acc;
    }
}

// Kernel 1: feat = x @ w^T via bf16 MFMA (f32 accum); a1 via f32 dot x.v1.
// (identical to R5 -- this is an attribution round)
__global__ __launch_bounds__(64) void gat_feat_kernel(
    const float* __restrict__ x, const unsigned short* __restrict__ wb,
    const float* __restrict__ v1, const float* __restrict__ a1bp,
    unsigned short* __restrict__ featb, float* __restrict__ a1)
{
    __shared__ __align__(16) unsigned short lds[32][64]; // 4 KB store-bounce tile
    const int lane = threadIdx.x & 63;
    const int r = lane & 15;   // A row / B col within 16-tile
    const int g = lane >> 4;   // k-group (8 contiguous k per group)
    const unsigned base = blockIdx.x * 32;   // N % 32 == 0: always full

    f32x4 xr[2][4][2];
    #pragma unroll
    for (int mt = 0; mt < 2; ++mt) {
        const float* xrow = x + (size_t)(base + mt * 16 + r) * IN_F + g * 8;
        #pragma unroll
        for (int ks = 0; ks < 4; ++ks) {
            xr[mt][ks][0] = __builtin_nontemporal_load((const f32x4*)(xrow + ks * 32));
            xr[mt][ks][1] = __builtin_nontemporal_load((const f32x4*)(xrow + ks * 32 + 4));
        }
    }

    f32x4 acc[2][4];
    #pragma unroll
    for (int mt = 0; mt < 2; ++mt)
        #pragma unroll
        for (int ft = 0; ft < 4; ++ft) acc[mt][ft] = (f32x4){0.f, 0.f, 0.f, 0.f};
    float p1[2] = {0.f, 0.f};

    #pragma unroll
    for (int ks = 0; ks < 4; ++ks) {
        short8 bf[4];
        #pragma unroll
        for (int ft = 0; ft < 4; ++ft)
            bf[ft] = *(const short8*)(wb + (ft * 16 + r) * IN_F + ks * 32 + g * 8);
        const float* vp1 = v1 + ks * 32 + g * 8;
        f32x4 v10 = *(const f32x4*)(vp1), v11 = *(const f32x4*)(vp1 + 4);
        #pragma unroll
        for (int mt = 0; mt < 2; ++mt) {
            f32x4 x0 = xr[mt][ks][0], x1 = xr[mt][ks][1];
            #pragma unroll
            for (int j = 0; j < 4; ++j)
                p1[mt] += x0[j] * v10[j] + x1[j] * v11[j];
            u32x4 au;
            au[0] = pack2bf(x0[0], x0[1]);
            au[1] = pack2bf(x0[2], x0[3]);
            au[2] = pack2bf(x1[0], x1[1]);
            au[3] = pack2bf(x1[2], x1[3]);
            short8 af; __builtin_memcpy(&af, &au, 16);
            #pragma unroll
            for (int ft = 0; ft < 4; ++ft)
                acc[mt][ft] = __builtin_amdgcn_mfma_f32_16x16x32_bf16(af, bf[ft], acc[mt][ft], 0, 0, 0);
        }
    }

    #pragma unroll
    for (int mt = 0; mt < 2; ++mt) {
        p1[mt] += __shfl_xor(p1[mt], 16, 64);
        p1[mt] += __shfl_xor(p1[mt], 32, 64);
    }
    if (lane < 16) {
        float b1 = a1bp[0];
        #pragma unroll
        for (int mt = 0; mt < 2; ++mt)
            a1[base + mt * 16 + lane] = p1[mt] + b1;
    }

    #pragma unroll
    for (int mt = 0; mt < 2; ++mt)
        #pragma unroll
        for (int ft = 0; ft < 4; ++ft) {
            const int cp = (ft * 16 + r) ^ (g << 4);
            #pragma unroll
            for (int reg = 0; reg < 4; ++reg)
                lds[mt * 16 + g * 4 + reg][cp] = f2bf(acc[mt][ft][reg]);
        }
    char* gdst = (char*)featb + (size_t)base * (OUT_F * 2);
    #pragma unroll
    for (int t = 0; t < 4; ++t) {
        const int row = t * 8 + (lane >> 3);
        const int cl  = (lane & 7) * 8;
        const int cp  = cl ^ (((row >> 2) & 3) << 4);
        i32x4 v = *(const i32x4*)(&lds[row][cp]);
        *(i32x4*)(gdst + (size_t)row * 128 + cl * 2) = v;
    }
}

#define BFLO(w_) __uint_as_float((w_) << 16)
#define BFHI(w_) __uint_as_float((w_) & 0xffff0000u)

// Kernel 2: identical to R5 (attribution round).
__global__ __launch_bounds__(256) void gat_agg_kernel(
    const int* __restrict__ dst, const unsigned short* __restrict__ featb,
    const float* __restrict__ a1, const float* __restrict__ a2w,
    const float* __restrict__ a2bp, const float* __restrict__ bias,
    float* __restrict__ out)
{
    const int wid  = threadIdx.x >> 6;
    const int lane = threadIdx.x & 63;
    const int e0 = lane & 15;
    const int sb = lane & 48;
    const int i = (blockIdx.x * 4 + wid) * 4 + (lane >> 4);

    const int d = dst[i * DEG + e0];

#define GATH(t) \
    const int de##t = __shfl(d, sb + (t), 64); \
    const u32x2 u##t = *(const u32x2*)(featb + (unsigned)de##t * OUT_F + e0 * 4);
    GATH(0)  GATH(1)  GATH(2)  GATH(3)
    GATH(4)  GATH(5)  GATH(6)  GATH(7)
    GATH(8)  GATH(9)  GATH(10) GATH(11)
    GATH(12) GATH(13) GATH(14) GATH(15)
#undef GATH

    const float a1i = a1[i] + a2bp[0];
    const f32x4 aw = *(const f32x4*)(a2w + e0 * 4);
    const f32x4 bv = *(const f32x4*)(bias + e0 * 4);

    float acc0 = 0.f, acc1 = 0.f, acc2 = 0.f, acc3 = 0.f, ssum = 0.f;
#define EDGE(t) { \
    const float f0 = BFLO(u##t[0]), f1 = BFHI(u##t[0]); \
    const float f2 = BFLO(u##t[1]), f3 = BFHI(u##t[1]); \
    float p = f0 * aw[0] + f1 * aw[1] + f2 * aw[2] + f3 * aw[3]; \
    p += __shfl_xor(p, 1, 64); p += __shfl_xor(p, 2, 64); \
    p += __shfl_xor(p, 4, 64); p += __shfl_xor(p, 8, 64); \
    const float z = a1i + p; \
    const float s = __expf(fmaxf(z, ALPHA * z)); \
    ssum += s; \
    acc0 += s * f0; acc1 += s * f1; acc2 += s * f2; acc3 += s * f3; }
    EDGE(0)  EDGE(1)  EDGE(2)  EDGE(3)
    EDGE(4)  EDGE(5)  EDGE(6)  EDGE(7)
    EDGE(8)  EDGE(9)  EDGE(10) EDGE(11)
    EDGE(12) EDGE(13) EDGE(14) EDGE(15)
#undef EDGE

    const float inv = 1.0f / ssum;
    f32x4 o;
    o[0] = acc0 * inv + bv[0];
    o[1] = acc1 * inv + bv[1];
    o[2] = acc2 * inv + bv[2];
    o[3] = acc3 * inv + bv[3];
    __builtin_nontemporal_store(o, (f32x4*)(out + (unsigned)i * OUT_F + e0 * 4));
}

extern "C" void kernel_launch(void* const* d_in, const int* in_sizes, int n_in,
                              void* d_out, int out_size, void* d_ws, size_t ws_size,
                              hipStream_t stream) {
    (void)in_sizes; (void)n_in; (void)out_size; (void)ws_size;
    const float* x    = (const float*)d_in[0];
    const int*   edges= (const int*)d_in[1];
    const float* w    = (const float*)d_in[2];
    const float* a1w  = (const float*)d_in[3];
    const float* a1b  = (const float*)d_in[4];
    const float* a2w  = (const float*)d_in[5];
    const float* a2b  = (const float*)d_in[6];
    const float* bias = (const float*)d_in[7];
    float* out = (float*)d_out;

    unsigned short* featb = (unsigned short*)d_ws;
    float* a1 = (float*)((char*)d_ws + (size_t)N_NODES * OUT_F * 2);
    float* v1 = a1 + N_NODES;
    unsigned short* wb = (unsigned short*)(v1 + IN_F);

    const int* dst = edges + (size_t)N_NODES * DEG;

    prep_kernel<<<dim3((OUT_F * IN_F + 255) / 256), dim3(256), 0, stream>>>(
        w, a1w, wb, v1);
    // ATTRIBUTION ROUND: feat x2, agg x4 (all idempotent -> output unchanged).
    // dur = prep + 2*feat + 4*agg  =>  agg = (dur - 131.2 + prep)/2, feat = 62.6 - agg.
    gat_feat_kernel<<<dim3(N_NODES / 32), dim3(64), 0, stream>>>(
        x, wb, v1, a1b, featb, a1);
    gat_feat_kernel<<<dim3(N_NODES / 32), dim3(64), 0, stream>>>(
        x, wb, v1, a1b, featb, a1);
    gat_agg_kernel<<<dim3(N_NODES / 16), dim3(256), 0, stream>>>(
        dst, featb, a1, a2w, a2b, bias, out);
    gat_agg_kernel<<<dim3(N_NODES / 16), dim3(256), 0, stream>>>(
        dst, featb, a1, a2w, a2b, bias, out);
    gat_agg_kernel<<<dim3(N_NODES / 16), dim3(256), 0, stream>>>(
        dst, featb, a1, a2w, a2b, bias, out);
    gat_agg_kernel<<<dim3(N_NODES / 16), dim3(256), 0, stream>>>(
        dst, featb, a1, a2w, a2b, bias, out);
}

// Round 7
// 60.136 us; speedup vs baseline: 2.9648x; 2.9648x over previous
//
#include <hip/hip_runtime.h>
#include <hip/hip_bf16.h>
#include <stdint.h>

#define N_NODES 100000
#define DEG 16
#define IN_F 128
#define OUT_F 64
#define ALPHA 0.2f

typedef __attribute__((ext_vector_type(8))) short short8;
typedef __attribute__((ext_vector_type(4))) float f32x4;
typedef __attribute__((ext_vector_type(4))) int i32x4;
typedef __attribute__((ext_vector_type(4))) unsigned int u32x4;
typedef __attribute__((ext_vector_type(2))) unsigned int u32x2;

static __device__ __forceinline__ unsigned int pack2bf(float lo, float hi) {
    // RTNE pair conversion; compiler emits v_cvt_pk_bf16_f32
    __hip_bfloat162 h = __float22bfloat162_rn(make_float2(lo, hi));
    unsigned int u; __builtin_memcpy(&u, &h, 4); return u;
}
static __device__ __forceinline__ unsigned short f2bf(float f) {
    __hip_bfloat16 h = __float2bfloat16(f);   // RTNE
    unsigned short u; __builtin_memcpy(&u, &h, 2); return u;
}

// Prep: w -> bf16 only (a1 comes from the MFMA accumulators; a2 is reconstructed
// in the agg kernel from gathered feat rows, so no v1/v2 exist).
__global__ __launch_bounds__(256) void prep_kernel(
    const float* __restrict__ w, unsigned short* __restrict__ wb)
{
    int idx = blockIdx.x * 256 + threadIdx.x;
    if (idx < OUT_F * IN_F) wb[idx] = f2bf(w[idx]);
}

// Kernel 1: feat = x @ w^T via bf16 MFMA (f32 accum); a1 from accumulators.
// R2-proven structure (measured ~8-9 us): 256-thr block = 4 waves x 32 nodes,
// bfrag hoisted before the K-loop, x loaded per-ks with plain f32x4 loads,
// per-wave unswizzled LDS bounce for the coalesced featb store.
__global__ __launch_bounds__(256) void gat_feat_kernel(
    const float* __restrict__ x, const unsigned short* __restrict__ wb,
    const float* __restrict__ a1w, const float* __restrict__ a1bp,
    unsigned short* __restrict__ featb, float* __restrict__ a1)
{
    __shared__ __align__(16) unsigned short lds[4][32][64]; // per-wave store-bounce tile
    const int wid  = threadIdx.x >> 6;
    const int lane = threadIdx.x & 63;
    const int r = lane & 15;   // A row / B col within 16-tile
    const int g = lane >> 4;   // k-group (8 contiguous k per group)
    const int base = (blockIdx.x * 4 + wid) * 32;
    if (base >= N_NODES) return;   // N % 32 == 0: active waves always full

    // B fragments hoisted (bf16, pre-converted): lane holds w[ft*16+r][ks*32+g*8 .. +7]
    short8 bfrag[4][4];
    #pragma unroll
    for (int ft = 0; ft < 4; ++ft)
        #pragma unroll
        for (int ks = 0; ks < 4; ++ks)
            bfrag[ft][ks] = *(const short8*)(wb + (ft * 16 + r) * IN_F + ks * 32 + g * 8);

    f32x4 acc[2][4];
    #pragma unroll
    for (int mt = 0; mt < 2; ++mt)
        #pragma unroll
        for (int ft = 0; ft < 4; ++ft) acc[mt][ft] = (f32x4){0.f, 0.f, 0.f, 0.f};

    #pragma unroll
    for (int mt = 0; mt < 2; ++mt) {
        const float* xrow = x + (size_t)(base + mt * 16 + r) * IN_F;
        #pragma unroll
        for (int ks = 0; ks < 4; ++ks) {
            const float* xp = xrow + ks * 32 + g * 8;
            f32x4 x0 = *(const f32x4*)(xp);
            f32x4 x1 = *(const f32x4*)(xp + 4);
            u32x4 au;
            au[0] = pack2bf(x0[0], x0[1]);
            au[1] = pack2bf(x0[2], x0[3]);
            au[2] = pack2bf(x1[0], x1[1]);
            au[3] = pack2bf(x1[2], x1[3]);
            short8 af; __builtin_memcpy(&af, &au, 16);
            #pragma unroll
            for (int ft = 0; ft < 4; ++ft)
                acc[mt][ft] = __builtin_amdgcn_mfma_f32_16x16x32_bf16(af, bfrag[ft][ks], acc[mt][ft], 0, 0, 0);
        }
    }
    // C/D layout (HW-verified): col = lane&15 -> feature ft*16+r; row = g*4+reg -> node mt*16+g*4+reg

    // a1 = feat @ a1w + b from the f32 accumulators (reduce across r-lanes)
    float w1v[4];
    #pragma unroll
    for (int ft = 0; ft < 4; ++ft) w1v[ft] = a1w[ft * 16 + r];
    float p1[2][4] = {{0.f,0.f,0.f,0.f},{0.f,0.f,0.f,0.f}};
    #pragma unroll
    for (int mt = 0; mt < 2; ++mt)
        #pragma unroll
        for (int ft = 0; ft < 4; ++ft)
            #pragma unroll
            for (int reg = 0; reg < 4; ++reg)
                p1[mt][reg] += acc[mt][ft][reg] * w1v[ft];
    #pragma unroll
    for (int m = 1; m <= 8; m <<= 1)
        #pragma unroll
        for (int mt = 0; mt < 2; ++mt)
            #pragma unroll
            for (int reg = 0; reg < 4; ++reg)
                p1[mt][reg] += __shfl_xor(p1[mt][reg], m, 64);
    if (r == 0) {
        float b1 = a1bp[0];
        #pragma unroll
        for (int mt = 0; mt < 2; ++mt)
            #pragma unroll
            for (int reg = 0; reg < 4; ++reg)
                a1[base + mt * 16 + g * 4 + reg] = p1[mt][reg] + b1;
    }

    // feat -> bf16, bounce through LDS so the global store is fully coalesced
    #pragma unroll
    for (int mt = 0; mt < 2; ++mt)
        #pragma unroll
        for (int ft = 0; ft < 4; ++ft)
            #pragma unroll
            for (int reg = 0; reg < 4; ++reg)
                lds[wid][mt * 16 + g * 4 + reg][ft * 16 + r] = f2bf(acc[mt][ft][reg]);
    // same-wave LDS RAW: compiler inserts lgkmcnt wait; tile is wave-private (no barrier)
    const char* lsrc = (const char*)(&lds[wid][0][0]);
    char* gdst = (char*)featb + (size_t)base * (OUT_F * 2);
    #pragma unroll
    for (int t = 0; t < 4; ++t) {
        i32x4 v = *(const i32x4*)(lsrc + t * 1024 + lane * 16);
        *(i32x4*)(gdst + t * 1024 + lane * 16) = v;
    }
}

#define BFLO(w_) __uint_as_float((w_) << 16)
#define BFHI(w_) __uint_as_float((w_) & 0xffff0000u)

// Kernel 2 (unchanged from R5, measured ~26 us): per-node scores + gather-aggregate.
// One wave = 4 nodes x 16 lanes. For each edge t the 16-lane group cooperatively
// gathers row dst_t (16 x 8B = one 128B line, ONE L2 request) and reconstructs
// a2[dst_t] = feat[dst_t].a2w in-register (kills the 1.6M random a2 gathers).
// All 16 gathers are NAMED registers (no alloca-to-LDS spill) issued up front.
__global__ __launch_bounds__(256) void gat_agg_kernel(
    const int* __restrict__ dst, const unsigned short* __restrict__ featb,
    const float* __restrict__ a1, const float* __restrict__ a2w,
    const float* __restrict__ a2bp, const float* __restrict__ bias,
    float* __restrict__ out)
{
    const int wid  = threadIdx.x >> 6;
    const int lane = threadIdx.x & 63;
    const int e0 = lane & 15;
    const int sb = lane & 48;
    const int i = (blockIdx.x * 4 + wid) * 4 + (lane >> 4);   // N % 16 == 0: exact

    const int d = dst[i * DEG + e0];

#define GATH(t) \
    const int de##t = __shfl(d, sb + (t), 64); \
    const u32x2 u##t = *(const u32x2*)(featb + (unsigned)de##t * OUT_F + e0 * 4);
    GATH(0)  GATH(1)  GATH(2)  GATH(3)
    GATH(4)  GATH(5)  GATH(6)  GATH(7)
    GATH(8)  GATH(9)  GATH(10) GATH(11)
    GATH(12) GATH(13) GATH(14) GATH(15)
#undef GATH

    const float a1i = a1[i] + a2bp[0];              // fold a2 bias into the constant
    const f32x4 aw = *(const f32x4*)(a2w + e0 * 4);
    const f32x4 bv = *(const f32x4*)(bias + e0 * 4);

    float acc0 = 0.f, acc1 = 0.f, acc2 = 0.f, acc3 = 0.f, ssum = 0.f;
#define EDGE(t) { \
    const float f0 = BFLO(u##t[0]), f1 = BFHI(u##t[0]); \
    const float f2 = BFLO(u##t[1]), f3 = BFHI(u##t[1]); \
    float p = f0 * aw[0] + f1 * aw[1] + f2 * aw[2] + f3 * aw[3]; \
    p += __shfl_xor(p, 1, 64); p += __shfl_xor(p, 2, 64); \
    p += __shfl_xor(p, 4, 64); p += __shfl_xor(p, 8, 64); \
    const float z = a1i + p; \
    const float s = __expf(fmaxf(z, ALPHA * z)); \
    ssum += s; \
    acc0 += s * f0; acc1 += s * f1; acc2 += s * f2; acc3 += s * f3; }
    EDGE(0)  EDGE(1)  EDGE(2)  EDGE(3)
    EDGE(4)  EDGE(5)  EDGE(6)  EDGE(7)
    EDGE(8)  EDGE(9)  EDGE(10) EDGE(11)
    EDGE(12) EDGE(13) EDGE(14) EDGE(15)
#undef EDGE

    const float inv = 1.0f / ssum;
    f32x4 o;
    o[0] = acc0 * inv + bv[0];
    o[1] = acc1 * inv + bv[1];
    o[2] = acc2 * inv + bv[2];
    o[3] = acc3 * inv + bv[3];
    __builtin_nontemporal_store(o, (f32x4*)(out + (unsigned)i * OUT_F + e0 * 4));
}

extern "C" void kernel_launch(void* const* d_in, const int* in_sizes, int n_in,
                              void* d_out, int out_size, void* d_ws, size_t ws_size,
                              hipStream_t stream) {
    (void)in_sizes; (void)n_in; (void)out_size; (void)ws_size;
    const float* x    = (const float*)d_in[0];
    const int*   edges= (const int*)d_in[1];   // [2, E] int32, row0=src, row1=dst
    const float* w    = (const float*)d_in[2];
    const float* a1w  = (const float*)d_in[3];
    const float* a1b  = (const float*)d_in[4];
    const float* a2w  = (const float*)d_in[5];
    const float* a2b  = (const float*)d_in[6];
    const float* bias = (const float*)d_in[7];
    float* out = (float*)d_out;

    // ws layout (16B-aligned): featb | a1 | wb
    unsigned short* featb = (unsigned short*)d_ws;                       // N*64 bf16 = 12.8 MB
    float* a1 = (float*)((char*)d_ws + (size_t)N_NODES * OUT_F * 2);
    unsigned short* wb = (unsigned short*)(a1 + N_NODES);

    const int* dst = edges + (size_t)N_NODES * DEG; // edges[1]

    prep_kernel<<<dim3((OUT_F * IN_F + 255) / 256), dim3(256), 0, stream>>>(w, wb);
    gat_feat_kernel<<<dim3((N_NODES + 127) / 128), dim3(256), 0, stream>>>(
        x, wb, a1w, a1b, featb, a1);
    gat_agg_kernel<<<dim3(N_NODES / 16), dim3(256), 0, stream>>>(
        dst, featb, a1, a2w, a2b, bias, out);
}